// Round 10
// baseline (185.394 us; speedup 1.0000x reference)
//
#include <hip/hip_runtime.h>
#include <stdint.h>

// Problem constants
#define B_ 2
#define S_ 2048
#define H_ 1024
#define NH_ 16
#define HD_ 64
#define M_ 4096            // B*S
#define LOG2E 1.44269504089f

typedef unsigned short u16;
typedef __bf16 bf16x8 __attribute__((ext_vector_type(8)));
typedef float  f32x4  __attribute__((ext_vector_type(4)));

#if __has_builtin(__builtin_amdgcn_exp2f)
#define EXP2(x) __builtin_amdgcn_exp2f(x)
#else
#define EXP2(x) exp2f(x)
#endif

#define WAITV4() asm volatile("s_waitcnt vmcnt(4)" ::: "memory")
#define WAITV0() asm volatile("s_waitcnt vmcnt(0)" ::: "memory")
#define SCHED0() __builtin_amdgcn_sched_barrier(0)

__device__ inline u16 f2bf(float f) {
  union { float f; uint32_t u; } a; a.f = f;
  uint32_t r = a.u + 0x7FFFu + ((a.u >> 16) & 1u);
  return (u16)(r >> 16);
}
__device__ inline float bf2f(u16 v) {
  union { uint32_t u; float f; } a; a.u = ((uint32_t)v) << 16; return a.f;
}

__device__ inline void gload_lds16(const void* g, void* l) {
  __builtin_amdgcn_global_load_lds((const __attribute__((address_space(1))) void*)g,
                                   (__attribute__((address_space(3))) void*)l, 16, 0, 0);
}

// ---------------- Kernel 1: f32 -> bf16 convert; W' = W + 4*LB*A folded; mask*log2e ----------------
__global__ __launch_bounds__(256) void cvt_kernel(
    const float* __restrict__ x,
    const float* __restrict__ wq, const float* __restrict__ wk, const float* __restrict__ wv,
    const float* __restrict__ Aq, const float* __restrict__ Ak, const float* __restrict__ Av,
    const float* __restrict__ LBq, const float* __restrict__ LBk, const float* __restrict__ LBv,
    const float* __restrict__ amask,
    u16* __restrict__ xbf, u16* __restrict__ wbf, float* __restrict__ maskl2e) {
  const int XN = M_ * H_;            // 4194304
  const int WN = H_ * H_;            // 1048576
  const int total = XN + 3 * WN;
  int idx = (blockIdx.x * 256 + threadIdx.x) * 4;
  if (idx < XN) {
    float4 v = *(const float4*)(x + idx);
    *(ushort4*)(xbf + idx) = make_ushort4(f2bf(v.x), f2bf(v.y), f2bf(v.z), f2bf(v.w));
  } else if (idx < total) {
    int j = idx - XN; int p = j >> 20; int off = j & (WN - 1);
    const float* W  = (p == 0) ? wq : (p == 1 ? wk : wv);
    const float* A  = (p == 0) ? Aq : (p == 1 ? Ak : Av);
    const float* LB = (p == 0) ? LBq : (p == 1 ? LBk : LBv);
    int n = off >> 10, k = off & 1023;
    float4 v  = *(const float4*)(W + off);
    f32x4 lb  = *(const f32x4*)&LB[n * 4];
    float4 a0 = *(const float4*)(A + k);
    float4 a1 = *(const float4*)(A + 1024 + k);
    float4 a2 = *(const float4*)(A + 2048 + k);
    float4 a3 = *(const float4*)(A + 3072 + k);
    v.x += 4.f * (lb.x * a0.x + lb.y * a1.x + lb.z * a2.x + lb.w * a3.x);
    v.y += 4.f * (lb.x * a0.y + lb.y * a1.y + lb.z * a2.y + lb.w * a3.y);
    v.z += 4.f * (lb.x * a0.z + lb.y * a1.z + lb.z * a2.z + lb.w * a3.z);
    v.w += 4.f * (lb.x * a0.w + lb.y * a1.w + lb.z * a2.w + lb.w * a3.w);
    *(ushort4*)(wbf + (p << 20) + off) = make_ushort4(f2bf(v.x), f2bf(v.y), f2bf(v.z), f2bf(v.w));
  } else {
    int mi = idx - total;                       // 0..4095: B*S mask values, pre-scaled
    if (mi < B_ * S_) {
      float4 mv = *(const float4*)(amask + mi);
      mv.x *= LOG2E; mv.y *= LOG2E; mv.z *= LOG2E; mv.w *= LOG2E;
      *(float4*)(maskl2e + mi) = mv;
    }
  }
}

// ---------------- Kernel 2: fused QKV GEMM, 3-buffer counted-vmcnt pipeline ----------------
template<int P>
__device__ __forceinline__ void gemm_body(
    const u16* __restrict__ xbf, const u16* __restrict__ wbf,
    const float* __restrict__ bias, u16* __restrict__ qkv,
    u16* __restrict__ As, u16* __restrict__ Bs) {
  const int n0 = blockIdx.x * 128;
  const int m0 = blockIdx.y * 128;
  const u16* Wp = wbf + (P << 20);
  const int tid = threadIdx.x, lane = tid & 63, w = tid >> 6;
  const int g = lane >> 4, q15 = lane & 15;
  const int wr = w >> 1, wc = w & 1;
  const f32x4 fzero = {0.f, 0.f, 0.f, 0.f};
  f32x4 acc[4][4];
#pragma unroll
  for (int mi = 0; mi < 4; ++mi)
#pragma unroll
    for (int ni = 0; ni < 4; ++ni) acc[mi][ni] = fzero;
  const int srow = lane >> 2;

  auto STAGE = [&](int buf, int k0) {
#pragma unroll
    for (int j = 0; j < 2; ++j) {
      int c = w * 2 + j;
      int row = c * 16 + srow;
      int uu = (lane & 3) ^ ((row >> 1) & 3);     // pre-swizzled global 16B-unit
      gload_lds16(xbf + (size_t)(m0 + row) * 1024 + k0 + uu * 8, As + buf * 4096 + c * 512);
      gload_lds16(Wp  + (size_t)(n0 + row) * 1024 + k0 + uu * 8, Bs + buf * 4096 + c * 512);
    }
  };

  STAGE(0, 0);
  STAGE(1, 32);
  int c0 = 0, c1 = 1, c2 = 2;
#pragma unroll 1
  for (int t = 0; t < 32; ++t) {
    if (t < 31) WAITV4(); else WAITV0();   // own stage(t) landed; stage(t+1) stays in flight
    SCHED0();
    __builtin_amdgcn_s_barrier();          // all waves' stage(t) landed; buf[c2] reads done
    if (t + 2 < 32) STAGE(c2, (t + 2) * 32);
    const u16* Ab = As + c0 * 4096;
    const u16* Bb = Bs + c0 * 4096;
    bf16x8 af[4], bfr[4];
#pragma unroll
    for (int mi = 0; mi < 4; ++mi) {
      int r = wr * 64 + mi * 16 + q15;
      af[mi] = *(const bf16x8*)&Ab[r * 32 + ((g ^ ((r >> 1) & 3)) * 8)];
    }
#pragma unroll
    for (int ni = 0; ni < 4; ++ni) {
      int r = wc * 64 + ni * 16 + q15;
      bfr[ni] = *(const bf16x8*)&Bb[r * 32 + ((g ^ ((r >> 1) & 3)) * 8)];
    }
    __builtin_amdgcn_s_setprio(1);
#pragma unroll
    for (int mi = 0; mi < 4; ++mi)
#pragma unroll
      for (int ni = 0; ni < 4; ++ni) {
        if (P == 2)
          acc[mi][ni] = __builtin_amdgcn_mfma_f32_16x16x32_bf16(af[mi], bfr[ni], acc[mi][ni], 0, 0, 0);
        else
          acc[mi][ni] = __builtin_amdgcn_mfma_f32_16x16x32_bf16(bfr[ni], af[mi], acc[mi][ni], 0, 0, 0);
      }
    __builtin_amdgcn_s_setprio(0);
    int tmp = c0; c0 = c1; c1 = c2; c2 = tmp;
  }

  // ---- epilogue: bias + vectorized ushort4 stores ----
  if (P != 2) {
#pragma unroll
    for (int ni = 0; ni < 4; ++ni) {
      int nb = n0 + wc * 64 + ni * 16 + g * 4;       // 4-aligned
      f32x4 bi = *(const f32x4*)&bias[nb];
      int h = nb >> 6, dbase = nb & 63;
#pragma unroll
      for (int mi = 0; mi < 4; ++mi) {
        int m = m0 + wr * 64 + mi * 16 + q15;
        int bb = m >> 11, s = m & 2047;
        size_t bhs = (size_t)(bb * 16 + h) * 2048 + s;
        float v0 = acc[mi][ni][0] + bi.x, v1 = acc[mi][ni][1] + bi.y;
        float v2 = acc[mi][ni][2] + bi.z, v3 = acc[mi][ni][3] + bi.w;
        size_t addr;
        if (P == 0) {
          const float qs = 0.125f * LOG2E;           // fold 1/sqrt(HD), log2(e)
          v0 *= qs; v1 *= qs; v2 *= qs; v3 *= qs;
          addr = bhs * 64 + dbase;
        } else {
          int pos = (((dbase >> 3) ^ (s & 7)) << 3) | (dbase & 7);   // K 16B-unit swz
          addr = 4194304 + bhs * 64 + pos;
        }
        *(ushort4*)&qkv[addr] = make_ushort4(f2bf(v0), f2bf(v1), f2bf(v2), f2bf(v3));
      }
    }
  } else {
    float biasv[4];
#pragma unroll
    for (int ni = 0; ni < 4; ++ni) biasv[ni] = bias[n0 + wc * 64 + ni * 16 + q15];
#pragma unroll
    for (int mi = 0; mi < 4; ++mi) {
      int mbase = m0 + wr * 64 + mi * 16 + g * 4;    // r -> consecutive s
      int bb = mbase >> 11, sbase = mbase & 2047;
      int sr = sbase & 31;
      int cba = (((sr >> 4) & 1) << 2) | (((sr >> 2) & 3) << 3);     // P-frag col perm
      int sp = (sbase & 32) | cba;
#pragma unroll
      for (int ni = 0; ni < 4; ++ni) {
        int n = n0 + wc * 64 + ni * 16 + q15;
        int d = n & 63, h = n >> 6;
        int spp = (((sp >> 3) ^ (d & 7)) << 3) | (sp & 7);           // 16B-unit swz
        size_t addr = 8388608 + ((size_t)(bb * 16 + h) * 64 + d) * 2048 + (sbase & ~63) + spp;
        *(ushort4*)&qkv[addr] = make_ushort4(
            f2bf(acc[mi][ni][0] + biasv[ni]), f2bf(acc[mi][ni][1] + biasv[ni]),
            f2bf(acc[mi][ni][2] + biasv[ni]), f2bf(acc[mi][ni][3] + biasv[ni]));
      }
    }
  }
}

__global__ __launch_bounds__(256) void qkv_gemm(
    const u16* __restrict__ xbf, const u16* __restrict__ wbf,
    const float* __restrict__ bq, const float* __restrict__ bk, const float* __restrict__ bv,
    u16* __restrict__ qkv) {
  __shared__ __align__(16) u16 As[3 * 4096];
  __shared__ __align__(16) u16 Bs[3 * 4096];
  switch (blockIdx.z) {
    case 0: gemm_body<0>(xbf, wbf, bq, qkv, As, Bs); break;
    case 1: gemm_body<1>(xbf, wbf, bk, qkv, As, Bs); break;
    default: gemm_body<2>(xbf, wbf, bv, qkv, As, Bs); break;
  }
}

// ---------------- Kernel 3: barrier-free streaming flash attention ----------------
// No LDS, no barriers. Each WAVE is an independent work item owning 32 q-rows
// (2 q-frags) and an 11-tile key range. K/V frags load global->reg (L2-hit; the
// baked XOR swizzle makes each frag-load 16 fully-used 64B sectors). Single-bank
// T14 pipeline: LOADV(t); QK(t) consumes K; LOADK(t+1) reuses K regs; softmax;
// PV(t) waits V. Per bh: pair qgroup p with 63-p (33 tiles), split 3x11 ->
// 3072 perfectly uniform wave-items = 768 blocks (3/CU, 12 waves/CU).
// Partials: phA s0 / phB s2 write unnormalized f32 -> out; others bf16 -> pacc.
__global__ __launch_bounds__(256, 3) void attn_kernel(
    const u16* __restrict__ qkv, const float* __restrict__ maskl2e, float* __restrict__ out,
    u16* __restrict__ pacc, float* __restrict__ pml) {
  const int bid = blockIdx.x;
  const int w = threadIdx.x >> 6, lane = threadIdx.x & 63;
  const int lg = lane >> 4, ql = lane & 15, m7 = ql & 7;
  const int xcd = bid & 7, jj = bid >> 3;
  const int wi = jj * 4 + w;                    // 0..383 within xcd
  const int bhl = wi / 96, r96 = wi - bhl * 96; // bh-local, residue
  const int bh = xcd * 4 + bhl;
  const int p = r96 / 3, s = r96 - (r96 / 3) * 3;
  const int lo = s * 11, hi = lo + 11;
  const int nA = (p >> 1) + 1;
  const int b = bh >> 4, h = bh & 15;
  const u16* Qb = qkv + (size_t)bh * 131072;
  const u16* Kb = qkv + 4194304 + (size_t)bh * 131072;
  const u16* Vb = qkv + 8388608 + (size_t)bh * 131072;   // [64][2048] transposed
  const float* Mb = maskl2e + b * 2048;
  const int u0 = lg ^ m7, u1 = (4 + lg) ^ m7;   // swizzled 16B-unit indices
  const f32x4 fzero = {0.f, 0.f, 0.f, 0.f};

  bf16x8 kA[8]; f32x4 mA[4]; bf16x8 vA[8];

#define LOADK(KT) do { const int kb_ = (KT) * 64; \
  _Pragma("unroll") for (int k16 = 0; k16 < 4; ++k16) { \
    kA[k16*2]   = *(const bf16x8*)&Kb[(size_t)(kb_ + k16*16 + ql) * 64 + u0 * 8]; \
    kA[k16*2+1] = *(const bf16x8*)&Kb[(size_t)(kb_ + k16*16 + ql) * 64 + u1 * 8]; \
    mA[k16]     = *(const f32x4*)&Mb[kb_ + k16*16 + lg*4]; } } while (0)
#define LOADV(KT) do { const int kb_ = (KT) * 64; \
  _Pragma("unroll") for (int dt = 0; dt < 4; ++dt) { \
    vA[dt*2]   = *(const bf16x8*)&Vb[(size_t)(dt*16 + ql) * 2048 + kb_ + u0 * 8]; \
    vA[dt*2+1] = *(const bf16x8*)&Vb[(size_t)(dt*16 + ql) * 2048 + kb_ + u1 * 8]; } } while (0)

#pragma unroll 1
  for (int ph = 0; ph < 2; ++ph) {
    const int G   = ph ? (63 - p) : p;                    // qgroup (32 rows)
    const int kt0 = ph ? ((lo - nA > 0) ? lo - nA : 0) : ((lo < nA) ? lo : nA);
    const int kt1 = ph ? (hi - nA) : ((hi < nA) ? hi : nA);
    if (kt0 >= kt1) continue;
    const int lastT = G >> 1;                             // diagonal tile index
    bf16x8 qf[2][2];
#pragma unroll
    for (int qg = 0; qg < 2; ++qg)
#pragma unroll
      for (int ks = 0; ks < 2; ++ks)
        qf[qg][ks] = *(const bf16x8*)&Qb[(size_t)(G*32 + qg*16 + ql) * 64 + ks*32 + lg*8];
    f32x4 acc[2][4];
#pragma unroll
    for (int qg = 0; qg < 2; ++qg)
#pragma unroll
      for (int dt = 0; dt < 4; ++dt) acc[qg][dt] = fzero;
    float mrun[2] = {-1e30f, -1e30f}, lrun[2] = {0.f, 0.f};

    LOADK(kt0);
#pragma unroll 1
    for (int kt = kt0; kt < kt1; ++kt) {
      LOADV(kt);                                  // V latency hides under QK+softmax
      const int kb = kt * 64;
      // ---- QK^T: C-init = mask; lane owns q=ql per q-frag ----
      f32x4 st[2][4];
      __builtin_amdgcn_s_setprio(1);
#pragma unroll
      for (int k16 = 0; k16 < 4; ++k16) {
        st[0][k16] = __builtin_amdgcn_mfma_f32_16x16x32_bf16(kA[k16*2],   qf[0][0], mA[k16], 0, 0, 0);
        st[0][k16] = __builtin_amdgcn_mfma_f32_16x16x32_bf16(kA[k16*2+1], qf[0][1], st[0][k16], 0, 0, 0);
        st[1][k16] = __builtin_amdgcn_mfma_f32_16x16x32_bf16(kA[k16*2],   qf[1][0], mA[k16], 0, 0, 0);
        st[1][k16] = __builtin_amdgcn_mfma_f32_16x16x32_bf16(kA[k16*2+1], qf[1][1], st[1][k16], 0, 0, 0);
      }
      __builtin_amdgcn_s_setprio(0);
      if (kt + 1 < kt1) LOADK(kt + 1);            // reuse kA/mA regs; K latency hides under softmax+PV
      // ---- online softmax per q-frag (log2 domain, defer-max THR=8) ----
      const bool needm = (kt == lastT);
      bf16x8 pfv0[2], pfv1[2];
#pragma unroll
      for (int qg = 0; qg < 2; ++qg) {
        const int q = G*32 + qg*16 + ql;
        float sc[16];
#pragma unroll
        for (int k16 = 0; k16 < 4; ++k16)
#pragma unroll
          for (int rr = 0; rr < 4; ++rr) {
            float sv = st[qg][k16][rr];
            if (needm) { int key = kb + k16*16 + lg*4 + rr; sv = (key > q) ? -1e30f : sv; }
            sc[k16*4 + rr] = sv;
          }
        float m8[8], m4[4];
#pragma unroll
        for (int i = 0; i < 8; ++i) m8[i] = fmaxf(sc[i], sc[i + 8]);
#pragma unroll
        for (int i = 0; i < 4; ++i) m4[i] = fmaxf(m8[i], m8[i + 4]);
        float pmax = fmaxf(fmaxf(m4[0], m4[1]), fmaxf(m4[2], m4[3]));
        if (!__all(pmax <= mrun[qg] + 8.f)) {
          float pm = fmaxf(pmax, __shfl_xor(pmax, 16, 64));
          pm = fmaxf(pm, __shfl_xor(pm, 32, 64));
          const float mt = fmaxf(mrun[qg], pm);
          const float scale = EXP2(mrun[qg] - mt);
          lrun[qg] *= scale;
#pragma unroll
          for (int dt = 0; dt < 4; ++dt) acc[qg][dt] *= scale;
          mrun[qg] = mt;
        }
        float pv[16];
#pragma unroll
        for (int i = 0; i < 16; ++i) pv[i] = EXP2(sc[i] - mrun[qg]);
        float s8[8], s4[4];
#pragma unroll
        for (int i = 0; i < 8; ++i) s8[i] = pv[i] + pv[i + 8];
#pragma unroll
        for (int i = 0; i < 4; ++i) s4[i] = s8[i] + s8[i + 4];
        lrun[qg] += (s4[0] + s4[1]) + (s4[2] + s4[3]);
        bf16x8* pf = qg ? pfv1 : pfv0;
#pragma unroll
        for (int ksub = 0; ksub < 2; ++ksub)
#pragma unroll
          for (int j2 = 0; j2 < 4; ++j2) {
            pf[ksub][j2]     = (__bf16)pv[ksub*8 + j2];
            pf[ksub][4 + j2] = (__bf16)pv[ksub*8 + 4 + j2];
          }
      }
      // ---- PV: V-frags shared by both q-frags (the q-reuse win) ----
      __builtin_amdgcn_s_setprio(1);
#pragma unroll
      for (int dt = 0; dt < 4; ++dt)
#pragma unroll
        for (int ksub = 0; ksub < 2; ++ksub) {
          acc[0][dt] = __builtin_amdgcn_mfma_f32_16x16x32_bf16(vA[dt*2+ksub], pfv0[ksub], acc[0][dt], 0, 0, 0);
          acc[1][dt] = __builtin_amdgcn_mfma_f32_16x16x32_bf16(vA[dt*2+ksub], pfv1[ksub], acc[1][dt], 0, 0, 0);
        }
      __builtin_amdgcn_s_setprio(0);
    }

    // ---- phase epilogue: unnormalized partial + (m,l) ----
    float lsum[2];
#pragma unroll
    for (int qg = 0; qg < 2; ++qg) {
      float ls = lrun[qg];
      ls += __shfl_xor(ls, 16, 64);
      ls += __shfl_xor(ls, 32, 64);
      lsum[qg] = ls;
    }
    const bool writer = ph ? (s == 2) : (s == 0);
    if (writer) {
#pragma unroll
      for (int qg = 0; qg < 2; ++qg)
#pragma unroll
        for (int dt = 0; dt < 4; ++dt)
          *(f32x4*)&out[((size_t)b * 2048 + G*32 + qg*16 + ql) * 1024 + h*64 + dt*16 + lg*4] = acc[qg][dt];
    } else {
      int rec;
      if (ph == 0) rec = bh * 10 + (G - 22);                      // s==1, G in 22..31
      else rec = (s == 1) ? (320 + bh * 32 + (G - 32))
                          : (1344 + bh * 20 + (G - 44));          // s==0 -> G>=44
      u16* pr = pacc + (size_t)rec * 2048;
#pragma unroll
      for (int qg = 0; qg < 2; ++qg)
#pragma unroll
        for (int dt = 0; dt < 4; ++dt)
          *(ushort4*)&pr[(qg*16 + ql) * 64 + dt*16 + lg*4] =
              make_ushort4(f2bf(acc[qg][dt][0]), f2bf(acc[qg][dt][1]),
                           f2bf(acc[qg][dt][2]), f2bf(acc[qg][dt][3]));
    }
    if (lg == 0) {
      float* pb = pml + (size_t)((bh * 64 + G) * 3 + s) * 64;
#pragma unroll
      for (int qg = 0; qg < 2; ++qg) {
        pb[(qg*16 + ql) * 2]     = mrun[qg];
        pb[(qg*16 + ql) * 2 + 1] = lsum[qg];
      }
    }
  }
#undef LOADK
#undef LOADV
}

// ---------------- Kernel 4: merge (closed-form contributors per qgroup) ----------------
__global__ __launch_bounds__(128) void merge_kernel(
    const u16* __restrict__ pacc, const float* __restrict__ pml, float* __restrict__ out) {
  const int mu = blockIdx.x;                 // 0..2047 = bh*64 + g
  const int bh = mu >> 6, g = mu & 63;
  const int b = bh >> 4, h = bh & 15;
  const int t = threadIdx.x;
  const int row = t >> 2, dc = (t & 3) * 16;
  const int pb = (bh * 64 + g) * 3;
  // contributor set (closed form; slot1 is always split 1, slot2 is split 0)
  const int wslot = (g < 32) ? 0 : 2;
  bool has1 = false, has2 = false;
  const u16 *bp1 = nullptr, *bp2 = nullptr;
  if (g < 32) {
    if (g >= 22) { has1 = true; bp1 = pacc + (size_t)(bh * 10 + (g - 22)) * 2048; }
  } else {
    has1 = true; bp1 = pacc + (size_t)(320 + bh * 32 + (g - 32)) * 2048;
    if (g >= 44) { has2 = true; bp2 = pacc + (size_t)(1344 + bh * 20 + (g - 44)) * 2048; }
  }
  const float mw = pml[(size_t)(pb + wslot) * 64 + row * 2];
  const float lw = pml[(size_t)(pb + wslot) * 64 + row * 2 + 1];
  float m1 = -1e30f, l1 = 0.f, m2 = -1e30f, l2 = 0.f;
  if (has1) { m1 = pml[(size_t)(pb + 1) * 64 + row * 2]; l1 = pml[(size_t)(pb + 1) * 64 + row * 2 + 1]; }
  if (has2) { m2 = pml[(size_t)(pb + 0) * 64 + row * 2]; l2 = pml[(size_t)(pb + 0) * 64 + row * 2 + 1]; }
  const float M = fmaxf(mw, fmaxf(m1, m2));
  const float ww = EXP2(mw - M);
  const float w1 = has1 ? EXP2(m1 - M) : 0.f;
  const float w2 = has2 ? EXP2(m2 - M) : 0.f;
  const float inv = 1.f / (ww * lw + w1 * l1 + w2 * l2);
  float* op = out + ((size_t)b * 2048 + g * 32 + row) * 1024 + h * 64 + dc;
#pragma unroll
  for (int j2 = 0; j2 < 4; ++j2) {
    f32x4 o = *(const f32x4*)(op + j2 * 4);
    o *= ww;
    if (has1) {
      ushort4 u = *(const ushort4*)(bp1 + row * 64 + dc + j2 * 4);
      o[0] += w1 * bf2f(u.x); o[1] += w1 * bf2f(u.y); o[2] += w1 * bf2f(u.z); o[3] += w1 * bf2f(u.w);
    }
    if (has2) {
      ushort4 u = *(const ushort4*)(bp2 + row * 64 + dc + j2 * 4);
      o[0] += w2 * bf2f(u.x); o[1] += w2 * bf2f(u.y); o[2] += w2 * bf2f(u.z); o[3] += w2 * bf2f(u.w);
    }
    o *= inv;
    *(f32x4*)(op + j2 * 4) = o;
  }
}

// ---------------- launch ----------------
extern "C" void kernel_launch(void* const* d_in, const int* in_sizes, int n_in,
                              void* d_out, int out_size, void* d_ws, size_t ws_size,
                              hipStream_t stream) {
  const float* x  = (const float*)d_in[0];
  const float* am = (const float*)d_in[1];
  const float* Wq = (const float*)d_in[2];
  const float* bq = (const float*)d_in[3];
  const float* Aq = (const float*)d_in[4];
  const float* Bq = (const float*)d_in[5];
  const float* Wk = (const float*)d_in[6];
  const float* bk = (const float*)d_in[7];
  const float* Ak = (const float*)d_in[8];
  const float* Bk = (const float*)d_in[9];
  const float* Wv = (const float*)d_in[10];
  const float* bv = (const float*)d_in[11];
  const float* Av = (const float*)d_in[12];
  const float* Bv = (const float*)d_in[13];
  float* out = (float*)d_out;

  u16* xbf   = (u16*)d_ws;                     // 4194304 u16 = 8 MB
  u16* wbf   = xbf + 4194304;                  // 3145728 u16 = 6 MB
  u16* qkv   = wbf + 3145728;                  // 12582912 u16 = 24 MB
  float* mk  = (float*)(qkv + 12582912);       // 4096 f32 = 16 KB (mask*log2e)
  // partials reuse xbf/wbf (dead after qkv_gemm):
  u16* pacc  = xbf;                            // 1984 recs x 2048 u16 = 7.75 MB
  float* pml = (float*)wbf;                    // 2048x3 recs x 64 f32 = 1.5 MB

  cvt_kernel<<<7172, 256, 0, stream>>>(x, Wq, Wk, Wv, Aq, Ak, Av, Bq, Bk, Bv, am, xbf, wbf, mk);
  qkv_gemm<<<dim3(8, 32, 3), 256, 0, stream>>>(xbf, wbf, bq, bk, bv, qkv);
  attn_kernel<<<768, 256, 0, stream>>>(qkv, mk, out, pacc, pml);
  merge_kernel<<<2048, 128, 0, stream>>>(pacc, pml, out);
}

// Round 11
// 92.645 us; speedup vs baseline: 2.0011x; 2.0011x over previous
//
#include <hip/hip_runtime.h>
#include <stdint.h>

// Problem constants
#define B_ 2
#define S_ 2048
#define H_ 1024
#define NH_ 16
#define HD_ 64
#define M_ 4096            // B*S
#define LOG2E 1.44269504089f

typedef unsigned short u16;
typedef __bf16 bf16x8 __attribute__((ext_vector_type(8)));
typedef float  f32x4  __attribute__((ext_vector_type(4)));

#if __has_builtin(__builtin_amdgcn_exp2f)
#define EXP2(x) __builtin_amdgcn_exp2f(x)
#else
#define EXP2(x) exp2f(x)
#endif

#define WAITV4() asm volatile("s_waitcnt vmcnt(4)" ::: "memory")
#define WAITV0() asm volatile("s_waitcnt vmcnt(0)" ::: "memory")
#define SCHED0() __builtin_amdgcn_sched_barrier(0)

__device__ inline u16 f2bf(float f) {
  union { float f; uint32_t u; } a; a.f = f;
  uint32_t r = a.u + 0x7FFFu + ((a.u >> 16) & 1u);
  return (u16)(r >> 16);
}

__device__ inline void gload_lds16(const void* g, void* l) {
  __builtin_amdgcn_global_load_lds((const __attribute__((address_space(1))) void*)g,
                                   (__attribute__((address_space(3))) void*)l, 16, 0, 0);
}

// ---------------- Kernel 1: f32 -> bf16 convert; W' = W + 4*LB*A folded; mask*log2e ----------------
__global__ __launch_bounds__(256) void cvt_kernel(
    const float* __restrict__ x,
    const float* __restrict__ wq, const float* __restrict__ wk, const float* __restrict__ wv,
    const float* __restrict__ Aq, const float* __restrict__ Ak, const float* __restrict__ Av,
    const float* __restrict__ LBq, const float* __restrict__ LBk, const float* __restrict__ LBv,
    const float* __restrict__ amask,
    u16* __restrict__ xbf, u16* __restrict__ wbf, float* __restrict__ maskl2e) {
  const int XN = M_ * H_;            // 4194304
  const int WN = H_ * H_;            // 1048576
  const int total = XN + 3 * WN;
  int idx = (blockIdx.x * 256 + threadIdx.x) * 4;
  if (idx < XN) {
    float4 v = *(const float4*)(x + idx);
    *(ushort4*)(xbf + idx) = make_ushort4(f2bf(v.x), f2bf(v.y), f2bf(v.z), f2bf(v.w));
  } else if (idx < total) {
    int j = idx - XN; int p = j >> 20; int off = j & (WN - 1);
    const float* W  = (p == 0) ? wq : (p == 1 ? wk : wv);
    const float* A  = (p == 0) ? Aq : (p == 1 ? Ak : Av);
    const float* LB = (p == 0) ? LBq : (p == 1 ? LBk : LBv);
    int n = off >> 10, k = off & 1023;
    float4 v  = *(const float4*)(W + off);
    f32x4 lb  = *(const f32x4*)&LB[n * 4];
    float4 a0 = *(const float4*)(A + k);
    float4 a1 = *(const float4*)(A + 1024 + k);
    float4 a2 = *(const float4*)(A + 2048 + k);
    float4 a3 = *(const float4*)(A + 3072 + k);
    v.x += 4.f * (lb.x * a0.x + lb.y * a1.x + lb.z * a2.x + lb.w * a3.x);
    v.y += 4.f * (lb.x * a0.y + lb.y * a1.y + lb.z * a2.y + lb.w * a3.y);
    v.z += 4.f * (lb.x * a0.z + lb.y * a1.z + lb.z * a2.z + lb.w * a3.z);
    v.w += 4.f * (lb.x * a0.w + lb.y * a1.w + lb.z * a2.w + lb.w * a3.w);
    *(ushort4*)(wbf + (p << 20) + off) = make_ushort4(f2bf(v.x), f2bf(v.y), f2bf(v.z), f2bf(v.w));
  } else {
    int mi = idx - total;                       // 0..4095: B*S mask values, pre-scaled
    if (mi < B_ * S_) {
      float4 mv = *(const float4*)(amask + mi);
      mv.x *= LOG2E; mv.y *= LOG2E; mv.z *= LOG2E; mv.w *= LOG2E;
      *(float4*)(maskl2e + mi) = mv;
    }
  }
}

// ---------------- Kernel 2: fused QKV GEMM, 3-buffer counted-vmcnt pipeline ----------------
template<int P>
__device__ __forceinline__ void gemm_body(
    const u16* __restrict__ xbf, const u16* __restrict__ wbf,
    const float* __restrict__ bias, u16* __restrict__ qkv,
    u16* __restrict__ As, u16* __restrict__ Bs) {
  const int n0 = blockIdx.x * 128;
  const int m0 = blockIdx.y * 128;
  const u16* Wp = wbf + (P << 20);
  const int tid = threadIdx.x, lane = tid & 63, w = tid >> 6;
  const int g = lane >> 4, q15 = lane & 15;
  const int wr = w >> 1, wc = w & 1;
  const f32x4 fzero = {0.f, 0.f, 0.f, 0.f};
  f32x4 acc[4][4];
#pragma unroll
  for (int mi = 0; mi < 4; ++mi)
#pragma unroll
    for (int ni = 0; ni < 4; ++ni) acc[mi][ni] = fzero;
  const int srow = lane >> 2;

  auto STAGE = [&](int buf, int k0) {
#pragma unroll
    for (int j = 0; j < 2; ++j) {
      int c = w * 2 + j;
      int row = c * 16 + srow;
      int uu = (lane & 3) ^ ((row >> 1) & 3);     // pre-swizzled global 16B-unit
      gload_lds16(xbf + (size_t)(m0 + row) * 1024 + k0 + uu * 8, As + buf * 4096 + c * 512);
      gload_lds16(Wp  + (size_t)(n0 + row) * 1024 + k0 + uu * 8, Bs + buf * 4096 + c * 512);
    }
  };

  STAGE(0, 0);
  STAGE(1, 32);
  int c0 = 0, c1 = 1, c2 = 2;
#pragma unroll 1
  for (int t = 0; t < 32; ++t) {
    if (t < 31) WAITV4(); else WAITV0();   // own stage(t) landed; stage(t+1) stays in flight
    SCHED0();
    __builtin_amdgcn_s_barrier();          // all waves' stage(t) landed; buf[c2] reads done
    if (t + 2 < 32) STAGE(c2, (t + 2) * 32);
    const u16* Ab = As + c0 * 4096;
    const u16* Bb = Bs + c0 * 4096;
    bf16x8 af[4], bfr[4];
#pragma unroll
    for (int mi = 0; mi < 4; ++mi) {
      int r = wr * 64 + mi * 16 + q15;
      af[mi] = *(const bf16x8*)&Ab[r * 32 + ((g ^ ((r >> 1) & 3)) * 8)];
    }
#pragma unroll
    for (int ni = 0; ni < 4; ++ni) {
      int r = wc * 64 + ni * 16 + q15;
      bfr[ni] = *(const bf16x8*)&Bb[r * 32 + ((g ^ ((r >> 1) & 3)) * 8)];
    }
    __builtin_amdgcn_s_setprio(1);
#pragma unroll
    for (int mi = 0; mi < 4; ++mi)
#pragma unroll
      for (int ni = 0; ni < 4; ++ni) {
        if (P == 2)
          acc[mi][ni] = __builtin_amdgcn_mfma_f32_16x16x32_bf16(af[mi], bfr[ni], acc[mi][ni], 0, 0, 0);
        else
          acc[mi][ni] = __builtin_amdgcn_mfma_f32_16x16x32_bf16(bfr[ni], af[mi], acc[mi][ni], 0, 0, 0);
      }
    __builtin_amdgcn_s_setprio(0);
    int tmp = c0; c0 = c1; c1 = c2; c2 = tmp;
  }

  // ---- epilogue: bias + vectorized ushort4 stores ----
  if (P != 2) {
#pragma unroll
    for (int ni = 0; ni < 4; ++ni) {
      int nb = n0 + wc * 64 + ni * 16 + g * 4;       // 4-aligned
      f32x4 bi = *(const f32x4*)&bias[nb];
      int h = nb >> 6, dbase = nb & 63;
#pragma unroll
      for (int mi = 0; mi < 4; ++mi) {
        int m = m0 + wr * 64 + mi * 16 + q15;
        int bb = m >> 11, s = m & 2047;
        size_t bhs = (size_t)(bb * 16 + h) * 2048 + s;
        float v0 = acc[mi][ni][0] + bi.x, v1 = acc[mi][ni][1] + bi.y;
        float v2 = acc[mi][ni][2] + bi.z, v3 = acc[mi][ni][3] + bi.w;
        size_t addr;
        if (P == 0) {
          const float qs = 0.125f * LOG2E;           // fold 1/sqrt(HD), log2(e)
          v0 *= qs; v1 *= qs; v2 *= qs; v3 *= qs;
          addr = bhs * 64 + dbase;
        } else {
          int pos = (((dbase >> 3) ^ (s & 7)) << 3) | (dbase & 7);   // K 16B-unit swz
          addr = 4194304 + bhs * 64 + pos;
        }
        *(ushort4*)&qkv[addr] = make_ushort4(f2bf(v0), f2bf(v1), f2bf(v2), f2bf(v3));
      }
    }
  } else {
    float biasv[4];
#pragma unroll
    for (int ni = 0; ni < 4; ++ni) biasv[ni] = bias[n0 + wc * 64 + ni * 16 + q15];
#pragma unroll
    for (int mi = 0; mi < 4; ++mi) {
      int mbase = m0 + wr * 64 + mi * 16 + g * 4;    // r -> consecutive s
      int bb = mbase >> 11, sbase = mbase & 2047;
      int sr = sbase & 31;
      int cba = (((sr >> 4) & 1) << 2) | (((sr >> 2) & 3) << 3);     // P-frag col perm
      int sp = (sbase & 32) | cba;
#pragma unroll
      for (int ni = 0; ni < 4; ++ni) {
        int n = n0 + wc * 64 + ni * 16 + q15;
        int d = n & 63, h = n >> 6;
        int spp = (((sp >> 3) ^ (d & 7)) << 3) | (sp & 7);           // 16B-unit swz
        size_t addr = 8388608 + ((size_t)(bb * 16 + h) * 64 + d) * 2048 + (sbase & ~63) + spp;
        *(ushort4*)&qkv[addr] = make_ushort4(
            f2bf(acc[mi][ni][0] + biasv[ni]), f2bf(acc[mi][ni][1] + biasv[ni]),
            f2bf(acc[mi][ni][2] + biasv[ni]), f2bf(acc[mi][ni][3] + biasv[ni]));
      }
    }
  }
}

__global__ __launch_bounds__(256) void qkv_gemm(
    const u16* __restrict__ xbf, const u16* __restrict__ wbf,
    const float* __restrict__ bq, const float* __restrict__ bk, const float* __restrict__ bv,
    u16* __restrict__ qkv) {
  __shared__ __align__(16) u16 As[3 * 4096];
  __shared__ __align__(16) u16 Bs[3 * 4096];
  switch (blockIdx.z) {
    case 0: gemm_body<0>(xbf, wbf, bq, qkv, As, Bs); break;
    case 1: gemm_body<1>(xbf, wbf, bk, qkv, As, Bs); break;
    default: gemm_body<2>(xbf, wbf, bv, qkv, As, Bs); break;
  }
}

// ---------------- Kernel 3: causal flash attention (R6 structure + reg-mask C-init + max3) ----------------
// 1024 blocks (one 64-q tile each), long-qt-first, 4 bh per XCD, 4 waves x 16 q.
// 2-buffer K/V LDS (32 KB) -> 4 blocks/CU. Mask enters as the QK MFMA C-init from
// registers (prefetched from L2) -- no mask LDS, 16 ds_reads/tile total.
__global__ __launch_bounds__(256, 4) void attn_kernel(
    const u16* __restrict__ qkv, const float* __restrict__ maskl2e, float* __restrict__ out) {
  const int bid = blockIdx.x;
  const int bh = (bid & 7) * 4 + ((bid >> 3) & 3);   // 4 bh per XCD -> K/V L2-resident
  const int qt = 31 - (bid >> 5);                    // long blocks first
  const int b = bh >> 4, h = bh & 15;
  const int tid = threadIdx.x, lane = tid & 63, w = tid >> 6;
  const int g = lane >> 4, ql = lane & 15;
  const u16* Qb = qkv + (size_t)bh * 131072;
  const u16* Kb = qkv + 4194304 + (size_t)bh * 131072;
  const u16* Vb = qkv + 8388608 + (size_t)bh * 131072;   // [64][2048] transposed
  const float* Mb = maskl2e + b * 2048;
  __shared__ __align__(16) u16 Ks[2][64][64];
  __shared__ __align__(16) u16 Vs[2][64][64];
  const f32x4 fzero = {0.f, 0.f, 0.f, 0.f};

  auto STAGE = [&](int nb, int kb) {
#pragma unroll
    for (int j = 0; j < 2; ++j) {
      int rl = w * 16 + j * 8 + (lane >> 3);
      gload_lds16(Kb + (size_t)(kb + rl) * 64 + (lane & 7) * 8, &Ks[nb][w * 16 + j * 8][0]);
      gload_lds16(Vb + (size_t)rl * 2048 + kb + (lane & 7) * 8, &Vs[nb][w * 16 + j * 8][0]);
    }
  };

  const int qw = qt * 64 + w * 16;
  const int q  = qw + ql;
  bf16x8 qf[2];
#pragma unroll
  for (int ks = 0; ks < 2; ++ks)
    qf[ks] = *(const bf16x8*)&Qb[(size_t)q * 64 + ks * 32 + g * 8];
  f32x4 acc[4];
#pragma unroll
  for (int dt = 0; dt < 4; ++dt) acc[dt] = fzero;
  float mrun = -1e30f, lrun = 0.f;
  const int nt = qt + 1;

  f32x4 mkC[4], mkN[4];
  STAGE(0, 0);
#pragma unroll
  for (int k16 = 0; k16 < 4; ++k16) mkC[k16] = *(const f32x4*)&Mb[k16 * 16 + g * 4];

#pragma unroll 1
  for (int t = 0; t < nt; ++t) {
    WAITV0();                       // own stage(t) + mask(t) landed
    SCHED0();
    __builtin_amdgcn_s_barrier();   // all waves staged(t); buf[(t+1)&1] reads done
    const int kb = t * 64;
    if (t + 1 < nt) {
      STAGE((t + 1) & 1, kb + 64);
#pragma unroll
      for (int k16 = 0; k16 < 4; ++k16) mkN[k16] = *(const f32x4*)&Mb[kb + 64 + k16 * 16 + g * 4];
    }
    const int cb = t & 1;
    // ---- QK^T: S^T, C-init = mask; lane owns q=ql; keys k16*16 + g*4 + r ----
    f32x4 st[4];
    __builtin_amdgcn_s_setprio(1);
#pragma unroll
    for (int k16 = 0; k16 < 4; ++k16) {
      bf16x8 kf0 = *(const bf16x8*)&Ks[cb][k16 * 16 + ql][(g ^ (ql & 7)) * 8];
      bf16x8 kf1 = *(const bf16x8*)&Ks[cb][k16 * 16 + ql][((4 + g) ^ (ql & 7)) * 8];
      st[k16] = __builtin_amdgcn_mfma_f32_16x16x32_bf16(kf0, qf[0], mkC[k16], 0, 0, 0);
      st[k16] = __builtin_amdgcn_mfma_f32_16x16x32_bf16(kf1, qf[1], st[k16], 0, 0, 0);
    }
    __builtin_amdgcn_s_setprio(0);
    // ---- online softmax (log2 domain, defer-max THR=8, max3 tree) ----
    const bool needm = (t == nt - 1);            // diagonal tile only (wave-uniform)
    float sc[16];
#pragma unroll
    for (int k16 = 0; k16 < 4; ++k16)
#pragma unroll
      for (int r = 0; r < 4; ++r) {
        float sv = st[k16][r];
        if (needm) { int key = kb + k16 * 16 + g * 4 + r; sv = (key > q) ? -1e30f : sv; }
        sc[k16 * 4 + r] = sv;
      }
    // v_max3 tree: 16 -> 6 -> 2 -> 1
    float t0 = fmaxf(fmaxf(sc[0],  sc[1]),  sc[2]);
    float t1 = fmaxf(fmaxf(sc[3],  sc[4]),  sc[5]);
    float t2 = fmaxf(fmaxf(sc[6],  sc[7]),  sc[8]);
    float t3 = fmaxf(fmaxf(sc[9],  sc[10]), sc[11]);
    float t4 = fmaxf(fmaxf(sc[12], sc[13]), sc[14]);
    float u0 = fmaxf(fmaxf(t0, t1), t2);
    float u1 = fmaxf(fmaxf(t3, t4), sc[15]);
    float pmax = fmaxf(u0, u1);
    if (!__all(pmax <= mrun + 8.f)) {            // rescale only when max grows
      float pm = fmaxf(pmax, __shfl_xor(pmax, 16, 64));
      pm = fmaxf(pm, __shfl_xor(pm, 32, 64));
      const float mt = fmaxf(mrun, pm);
      const float scale = EXP2(mrun - mt);
      lrun *= scale;
#pragma unroll
      for (int dt = 0; dt < 4; ++dt) acc[dt] *= scale;
      mrun = mt;
    }
    float pv[16];
#pragma unroll
    for (int i = 0; i < 16; ++i) pv[i] = EXP2(sc[i] - mrun);
    float s8[8], s4[4];
#pragma unroll
    for (int i = 0; i < 8; ++i) s8[i] = pv[i] + pv[i + 8];
#pragma unroll
    for (int i = 0; i < 4; ++i) s4[i] = s8[i] + s8[i + 4];
    lrun += (s4[0] + s4[1]) + (s4[2] + s4[3]);
    bf16x8 pfv[2];
#pragma unroll
    for (int ksub = 0; ksub < 2; ++ksub)
#pragma unroll
      for (int j = 0; j < 4; ++j) {
        pfv[ksub][j]     = (__bf16)pv[ksub * 8 + j];
        pfv[ksub][4 + j] = (__bf16)pv[ksub * 8 + 4 + j];
      }
    // ---- PV: acc^T[d][q] += V^T P ----
    __builtin_amdgcn_s_setprio(1);
#pragma unroll
    for (int dt = 0; dt < 4; ++dt)
#pragma unroll
      for (int ksub = 0; ksub < 2; ++ksub) {
        bf16x8 vf = *(const bf16x8*)&Vs[cb][dt * 16 + ql][((ksub * 4 + g) ^ (ql & 7)) * 8];
        acc[dt] = __builtin_amdgcn_mfma_f32_16x16x32_bf16(vf, pfv[ksub], acc[dt], 0, 0, 0);
      }
    __builtin_amdgcn_s_setprio(0);
#pragma unroll
    for (int k16 = 0; k16 < 4; ++k16) mkC[k16] = mkN[k16];
  }

  float lsum = lrun;
  lsum += __shfl_xor(lsum, 16, 64);
  lsum += __shfl_xor(lsum, 32, 64);
  const float inv = 1.f / lsum;
#pragma unroll
  for (int dt = 0; dt < 4; ++dt) {
    f32x4 o = acc[dt] * inv;
    *(f32x4*)&out[((size_t)b * 2048 + q) * 1024 + h * 64 + dt * 16 + g * 4] = o;
  }
}

// ---------------- launch ----------------
extern "C" void kernel_launch(void* const* d_in, const int* in_sizes, int n_in,
                              void* d_out, int out_size, void* d_ws, size_t ws_size,
                              hipStream_t stream) {
  const float* x  = (const float*)d_in[0];
  const float* am = (const float*)d_in[1];
  const float* Wq = (const float*)d_in[2];
  const float* bq = (const float*)d_in[3];
  const float* Aq = (const float*)d_in[4];
  const float* Bq = (const float*)d_in[5];
  const float* Wk = (const float*)d_in[6];
  const float* bk = (const float*)d_in[7];
  const float* Ak = (const float*)d_in[8];
  const float* Bk = (const float*)d_in[9];
  const float* Wv = (const float*)d_in[10];
  const float* bv = (const float*)d_in[11];
  const float* Av = (const float*)d_in[12];
  const float* Bv = (const float*)d_in[13];
  float* out = (float*)d_out;

  u16* xbf   = (u16*)d_ws;                     // 4194304 u16 = 8 MB
  u16* wbf   = xbf + 4194304;                  // 3145728 u16 = 6 MB
  u16* qkv   = wbf + 3145728;                  // 12582912 u16 = 24 MB
  float* mk  = (float*)(qkv + 12582912);       // 4096 f32 = 16 KB (mask*log2e)

  cvt_kernel<<<7172, 256, 0, stream>>>(x, Wq, Wk, Wv, Aq, Ak, Av, Bq, Bk, Bv, am, xbf, wbf, mk);
  qkv_gemm<<<dim3(8, 32, 3), 256, 0, stream>>>(xbf, wbf, bq, bk, bv, qkv);
  attn_kernel<<<1024, 256, 0, stream>>>(qkv, mk, out);
}